// Round 15
// baseline (1200.218 us; speedup 1.0000x reference)
//
#include <hip/hip_runtime.h>
#include <stdint.h>

// GlobalEmdModel: mlp1(128->256->512->512) -> segmax -> segbias trick ->
// mlp2(X@W4a + sb[seg] -> 512 -> segmax) ; bf16 MFMA GEMMs, fp32 epilogues.
// R15: occupancy structure: 128x128 tile, 4 waves, 64x64/wave (acc 64 AGPR),
//      launch_bounds(256,3) -> 3 waves/SIMD, LDS 32KB -> 3 blocks/CU.
//      Cross-BLOCK overlap (m97/m114 mechanism) replaces schedule tuning.
//      Keeps R13-verified: asm ds_read_b128, both-sides swizzle, counted
//      waits, raw barriers, m204 XCD swizzle + n-fastest decode.

typedef __bf16 bf16;
typedef __bf16 bf16x4 __attribute__((ext_vector_type(4)));
typedef __bf16 bf16x8 __attribute__((ext_vector_type(8)));
typedef float f32x4 __attribute__((ext_vector_type(4)));
typedef __attribute__((address_space(3))) char lds_char;

#define N_PTS 400000
#define ORD_NEG_INF 0x007FFFFFu  // f2ord(-inf)

__device__ __forceinline__ unsigned f2ord(float f) {
  unsigned u = __float_as_uint(f);
  return (u & 0x80000000u) ? ~u : (u | 0x80000000u);
}
__device__ __forceinline__ float ord2f(unsigned o) {
  unsigned u = (o & 0x80000000u) ? (o ^ 0x80000000u) : ~o;
  return __uint_as_float(u);
}

__device__ __forceinline__ void gld16(const bf16* g, lds_char* l) {
  __builtin_amdgcn_global_load_lds((const __attribute__((address_space(1))) void*)g,
                                   (__attribute__((address_space(3))) void*)l, 16, 0, 0);
}

// asm ds_read: invisible to SIInsertWaitcnts' LDS-DMA alias drain (R7 win).
#define DSR(dst, preg, IMM) \
  asm volatile("ds_read_b128 %0, %1 offset:%c2" : "=&v"(dst) : "v"(preg), "n"(IMM))

#define SCHED0 __builtin_amdgcn_sched_barrier(0)
#define LGKM0 do { asm volatile("s_waitcnt lgkmcnt(0)"); SCHED0; } while (0)
#define SBARR do { __builtin_amdgcn_s_barrier(); SCHED0; } while (0)
#define VMW0 do { asm volatile("s_waitcnt vmcnt(0)"); SCHED0; } while (0)

__global__ void k_init(unsigned* g_ord, unsigned* out_u) {
  int i = blockIdx.x * 256 + threadIdx.x;
  if (i < 64 * 512) { g_ord[i] = ORD_NEG_INF; out_u[i] = ORD_NEG_INF; }
}

__global__ void k_convX(const float* __restrict__ x, bf16* __restrict__ y, long n4) {
  long i = (long)blockIdx.x * 256 + threadIdx.x;
  long stride = (long)gridDim.x * 256;
  for (; i < n4; i += stride) {
    float4 v = ((const float4*)x)[i];
    bf16x4 o = {(bf16)v.x, (bf16)v.y, (bf16)v.z, (bf16)v.w};
    ((bf16x4*)y)[i] = o;
  }
}

// W [K][Nout] fp32 -> Wt [Nout][K] bf16
__global__ void k_convWt(const float* __restrict__ W, bf16* __restrict__ Wt, int K, int Nout) {
  int idx = blockIdx.x * 256 + threadIdx.x;
  if (idx < K * Nout) {
    int k = idx / Nout, c = idx - k * Nout;
    Wt[(size_t)c * K + k] = (bf16)W[idx];
  }
}

// sb[s][c] = b4[c] + sum_j g[s][j] * W4[128+j][c]
__global__ void k_segbias(const unsigned* __restrict__ g_ord, const float* __restrict__ W4,
                          const float* __restrict__ b4, float* __restrict__ sb) {
  const int s = blockIdx.x, c = threadIdx.x;
  __shared__ float gs[512];
  gs[c] = ord2f(g_ord[s * 512 + c]);
  __syncthreads();
  float acc = b4[c];
  for (int j = 0; j < 512; ++j) acc = fmaf(gs[j], W4[(size_t)(128 + j) * 512 + c], acc);
  sb[s * 512 + c] = acc;
}

__global__ void k_decode(unsigned* p, int n) {
  int i = blockIdx.x * 256 + threadIdx.x;
  if (i < n) { float f = ord2f(p[i]); ((float*)p)[i] = f; }
}

// 128x128 tile, 4 waves (wr=wid>>1, wc=wid&1), per-wave 64x64 output. BK=32.
// LDS: 2 bufs x 16KB = [A 8KB (8 rowgrps) | B 8KB (8 rowgrps)], rowgrp =
//   16 rows x 32 cols, stored slot = logical slot ^ ((row>>1)&3) (both-sides,
//   R9/R11-verified staging/read pair, counts halved).
// Per tile T: 8 asm ds_reads(buf T) -> STG(T+1) -> lgkm(0) -> 16 indep MFMA
//   -> vmcnt(0) -> s_barrier. 3 blocks/CU overlap each other's stalls.
template <int BIASMODE, bool RELU, int EPI, int K, int NOUT>
__launch_bounds__(256, 3)
__global__ void k_gemm(const bf16* __restrict__ A, const bf16* __restrict__ Bt,
                       const float* __restrict__ bias, const int* __restrict__ ids,
                       long row_off, bf16* __restrict__ out,
                       unsigned* __restrict__ outAtomic) {
  constexpr int NT = K / 32;     // 32-wide K-tiles (4/8/16)
  constexpr int NBX = NOUT / 128;
  __shared__ __align__(16) char sMem[32768];
  __shared__ int sIds[128];
  const int tid = threadIdx.x;
  const int wid = tid >> 6, lane = tid & 63;
  const int wr = wid >> 1, wc = wid & 1;
  const int lr = lane & 15, lk = lane >> 4;

  // linear id (N fastest) -> bijective XCD swizzle (m204; R13-verified form:
  // same-m column-blocks are w-consecutive -> co-XCD -> A panel shared in L2)
  const int nwg = NBX * (int)gridDim.y;
  const int orig = (int)blockIdx.y * NBX + (int)blockIdx.x;
  const int q = nwg >> 3, r = nwg & 7;
  const int xcd = orig & 7, lid = orig >> 3;
  const int wg = (xcd < r ? xcd * (q + 1) : r * (q + 1) + (xcd - r) * q) + lid;
  const int n0 = (wg % NBX) * 128;
  const int m0 = (wg / NBX) * 128;

  if constexpr (BIASMODE == 1 || EPI == 1) {
    if (tid < 128) {
      long gi = row_off + m0 + tid;
      if (gi > (long)N_PTS - 1) gi = (long)N_PTS - 1;
      sIds[tid] = ids[gi];
    }
  }
  SCHED0;  // ids load + ds_write fully before staging

  lds_char* lds3 = (lds_char*)sMem;

  // ---- staging (R9/R11-verified pattern): wave wid stages A rowgrps
  // {wid*2, wid*2+1} and B rowgrps {wid*2, wid*2+1}; 4 gld16/wave/tile.
  // lane l: row-in-grp = l>>2, stored slot = l&3, logical colblk =
  // (l&3) ^ ((l>>3)&3)  (pre-swizzled source, rule 21).
  const int rIn = lane >> 2;
  const int cblk = ((lane & 3) ^ ((lane >> 3) & 3)) * 8;
  const bf16* srcA[2]; lds_char* dstA[2];
  const bf16* srcB[2]; lds_char* dstB[2];
#pragma unroll
  for (int k = 0; k < 2; ++k) {
    const int g8 = wid * 2 + k;
    srcA[k] = A + (size_t)(m0 + g8 * 16 + rIn) * K + cblk;
    dstA[k] = lds3 + g8 * 1024 + lane * 16;
    srcB[k] = Bt + (size_t)(n0 + g8 * 16 + rIn) * K + cblk;
    dstB[k] = lds3 + 8192 + g8 * 1024 + lane * 16;
  }
  auto STG = [&](int tau) {
    if (tau < NT) {
      const int bo = (tau & 1) * 16384;
      const int ko = tau * 32;
#pragma unroll
      for (int k = 0; k < 2; ++k) gld16(srcA[k] + ko, dstA[k] + bo);
#pragma unroll
      for (int k = 0; k < 2; ++k) gld16(srcB[k] + ko, dstB[k] + bo);
    }
  };

  // ---- fragment read bases (R9/R11-verified): slot' = lk ^ ((row>>1)&3)
  const unsigned sl16 = (((unsigned)lk) ^ ((unsigned)(lr >> 1) & 3u)) * 16u;
  lds_char* vA = lds3 + wr * 4096 + lr * 64 + sl16;
  lds_char* vB = lds3 + 8192 + wc * 4096 + lr * 64 + sl16;

  bf16x8 aR[4], bR[4];
  f32x4 acc[4][4];
#pragma unroll
  for (int i = 0; i < 4; ++i)
#pragma unroll
    for (int j = 0; j < 4; ++j) acc[i][j] = {0.f, 0.f, 0.f, 0.f};

  // ---- prologue: stage tile 0, wait it + sIds ds_write, publish
  STG(0);
  asm volatile("s_waitcnt vmcnt(0) lgkmcnt(0)");
  SCHED0;
  SBARR;

#pragma unroll 1
  for (int t = 0; t < NT; ++t) {
    lds_char* pA = vA + (t & 1) * 16384;
    lds_char* pB = vB + (t & 1) * 16384;
    DSR(aR[0], pA, 0); DSR(aR[1], pA, 1024); DSR(aR[2], pA, 2048); DSR(aR[3], pA, 3072);
    DSR(bR[0], pB, 0); DSR(bR[1], pB, 1024); DSR(bR[2], pB, 2048); DSR(bR[3], pB, 3072);
    STG(t + 1);  // buf (t+1)&1: its tile-(t-1) readers retired before barrier(t-1)
    LGKM0;
    __builtin_amdgcn_s_setprio(1);
#pragma unroll
    for (int i = 0; i < 4; ++i)
#pragma unroll
      for (int j = 0; j < 4; ++j)
        acc[i][j] = __builtin_amdgcn_mfma_f32_16x16x32_bf16(aR[i], bR[j], acc[i][j], 0, 0, 0);
    __builtin_amdgcn_s_setprio(0);
    if (t < NT - 1) {
      VMW0;      // own 4 stage instr landed (issued a whole tile ago)
      SBARR;     // publish tile t+1
    }
  }

  if constexpr (EPI == 0) {
#pragma unroll
    for (int j = 0; j < 4; ++j) {
      const int col = n0 + wc * 64 + j * 16 + lr;
      float bcol = (BIASMODE == 0) ? bias[col] : 0.f;
#pragma unroll
      for (int i = 0; i < 4; ++i) {
#pragma unroll
        for (int q2 = 0; q2 < 4; ++q2) {
          const int rl = wr * 64 + i * 16 + lk * 4 + q2;
          float v = acc[i][j][q2];
          if constexpr (BIASMODE == 0) v += bcol;
          else v += bias[(size_t)sIds[rl] * 512 + col];
          if constexpr (RELU) v = fmaxf(v, 0.f);
          out[(size_t)(m0 + rl) * NOUT + col] = (bf16)v;
        }
      }
    }
  } else {
    const int sLo = sIds[wr * 64], sHi = sIds[wr * 64 + 63];
#pragma unroll
    for (int j = 0; j < 4; ++j) {
      const int col = n0 + wc * 64 + j * 16 + lr;
      const float bcol = bias[col];
      for (int s = sLo; s <= sHi; ++s) {
        float m = -__builtin_inff();
#pragma unroll
        for (int i = 0; i < 4; ++i)
#pragma unroll
          for (int q2 = 0; q2 < 4; ++q2) {
            const int rl = wr * 64 + i * 16 + lk * 4 + q2;
            const bool rv = (row_off + m0 + rl) < (long)N_PTS;
            float v = acc[i][j][q2] + bcol;
            m = (sIds[rl] == s && rv) ? fmaxf(m, v) : m;
          }
        m = fmaxf(m, __shfl_xor(m, 16));
        m = fmaxf(m, __shfl_xor(m, 32));
        if (lane < 16) atomicMax(&outAtomic[(size_t)s * 512 + col], f2ord(m));
      }
    }
  }
}

static inline long lmin(long a, long b) { return a < b ? a : b; }

extern "C" void kernel_launch(void* const* d_in, const int* in_sizes, int n_in,
                              void* d_out, int out_size, void* d_ws, size_t ws_size,
                              hipStream_t stream) {
  const float* pos = (const float*)d_in[0];
  const int* ids = (const int*)d_in[1];
  const float* W1 = (const float*)d_in[2]; const float* b1 = (const float*)d_in[3];
  const float* W2 = (const float*)d_in[4]; const float* b2 = (const float*)d_in[5];
  const float* W3 = (const float*)d_in[6]; const float* b3 = (const float*)d_in[7];
  const float* W4 = (const float*)d_in[8]; const float* b4 = (const float*)d_in[9];
  const float* W5 = (const float*)d_in[10]; const float* b5 = (const float*)d_in[11];

  char* ws = (char*)d_ws;
  size_t off = 0;
  auto alloc = [&](size_t bytes) -> char* {
    off = (off + 255) & ~(size_t)255;
    char* p = ws + off; off += bytes; return p;
  };
  bf16* Wt1  = (bf16*)alloc(128 * 256 * 2);
  bf16* Wt2  = (bf16*)alloc(256 * 512 * 2);
  bf16* Wt3  = (bf16*)alloc(512 * 512 * 2);
  bf16* Wt4a = (bf16*)alloc(128 * 512 * 2);
  bf16* Wt5  = (bf16*)alloc(512 * 512 * 2);
  unsigned* g_ord = (unsigned*)alloc(64 * 512 * 4);
  float* sb = (float*)alloc(64 * 512 * 4);
  // persistent bf16 X (+pad rows, defensive)
  bf16* Xbf = (bf16*)alloc((size_t)(N_PTS + 384) * 128 * 2);

  const size_t per_row = (256 + 512) * 2;  // h1 + h2
  size_t fixed_end = (off + 255) & ~(size_t)255;
  long avail = (long)ws_size - (long)fixed_end - 8192;
  long maxrows = avail / (long)per_row;
  long chunk = (maxrows - 256) & ~255L;  // multiple of 256 (hence of 128)
  if (chunk > N_PTS) chunk = N_PTS;
  if (chunk < 256) chunk = 256;
  long rows_alloc = chunk + 256;

  bf16* h1 = (bf16*)alloc((size_t)rows_alloc * 256 * 2);
  bf16* h2 = (bf16*)alloc((size_t)rows_alloc * 512 * 2);  // also z1 in phase 2

  k_init<<<dim3(128), dim3(256), 0, stream>>>(g_ord, (unsigned*)d_out);
  k_convWt<<<dim3((128 * 256 + 255) / 256), dim3(256), 0, stream>>>(W1, Wt1, 128, 256);
  k_convWt<<<dim3((256 * 512 + 255) / 256), dim3(256), 0, stream>>>(W2, Wt2, 256, 512);
  k_convWt<<<dim3((512 * 512 + 255) / 256), dim3(256), 0, stream>>>(W3, Wt3, 512, 512);
  k_convWt<<<dim3((128 * 512 + 255) / 256), dim3(256), 0, stream>>>(W4, Wt4a, 128, 512);
  k_convWt<<<dim3((512 * 512 + 255) / 256), dim3(256), 0, stream>>>(W5, Wt5, 512, 512);
  // one full-N conversion; pad rows stay 0xAA poison (finite bf16, masked later)
  k_convX<<<dim3(2048), dim3(256), 0, stream>>>(pos, Xbf, (long)N_PTS * 32);

  // phase 1: mlp1 + fused segmax -> g_ord
  for (long o = 0; o < N_PTS; o += chunk) {
    long rows = lmin(chunk, N_PTS - o);
    unsigned mb = (unsigned)((rows + 127) / 128);
    k_gemm<0, true, 0, 128, 256><<<dim3(2, mb), dim3(256), 0, stream>>>(Xbf + o * 128, Wt1, b1, ids, o, h1, nullptr);
    k_gemm<0, true, 0, 256, 512><<<dim3(4, mb), dim3(256), 0, stream>>>(h1, Wt2, b2, ids, o, h2, nullptr);
    k_gemm<0, false, 1, 512, 512><<<dim3(4, mb), dim3(256), 0, stream>>>(h2, Wt3, b3, ids, o, nullptr, g_ord);
  }
  k_segbias<<<dim3(64), dim3(512), 0, stream>>>(g_ord, W4, b4, sb);
  // phase 2: z1 = relu(X@W4a + sb[seg]); out = segmax(z1@W5 + b5)
  for (long o = 0; o < N_PTS; o += chunk) {
    long rows = lmin(chunk, N_PTS - o);
    unsigned mb = (unsigned)((rows + 127) / 128);
    k_gemm<1, true, 0, 128, 512><<<dim3(4, mb), dim3(256), 0, stream>>>(Xbf + o * 128, Wt4a, sb, ids, o, h2, nullptr);
    k_gemm<0, false, 1, 512, 512><<<dim3(4, mb), dim3(256), 0, stream>>>(h2, Wt5, b5, ids, o, nullptr, (unsigned*)d_out);
  }
  k_decode<<<dim3(128), dim3(256), 0, stream>>>((unsigned*)d_out, 64 * 512);
}

// Round 16
// 1093.506 us; speedup vs baseline: 1.0976x; 1.0976x over previous
//
#include <hip/hip_runtime.h>
#include <stdint.h>

// GlobalEmdModel: mlp1(128->256->512->512) -> segmax -> segbias trick ->
// mlp2(X@W4a + sb[seg] -> 512 -> segmax) ; bf16 MFMA GEMMs, fp32 epilogues.
// R16: R13 + counted-lgkm k0/k1 split inside each phase: reads issued as
//      {k0 set, k1 set}; lgkm(|k1|) releases the 8 k0-MFMAs while k1 reads
//      complete underneath; MFMAs reordered all-k0-then-all-k1 (also kills
//      dependent same-acc pairs). Everything else byte-identical to R13.

typedef __bf16 bf16;
typedef __bf16 bf16x4 __attribute__((ext_vector_type(4)));
typedef __bf16 bf16x8 __attribute__((ext_vector_type(8)));
typedef float f32x4 __attribute__((ext_vector_type(4)));
typedef __attribute__((address_space(3))) char lds_char;

#define N_PTS 400000
#define ORD_NEG_INF 0x007FFFFFu  // f2ord(-inf)

__device__ __forceinline__ unsigned f2ord(float f) {
  unsigned u = __float_as_uint(f);
  return (u & 0x80000000u) ? ~u : (u | 0x80000000u);
}
__device__ __forceinline__ float ord2f(unsigned o) {
  unsigned u = (o & 0x80000000u) ? (o ^ 0x80000000u) : ~o;
  return __uint_as_float(u);
}

__device__ __forceinline__ void gld16(const bf16* g, lds_char* l) {
  __builtin_amdgcn_global_load_lds((const __attribute__((address_space(1))) void*)g,
                                   (__attribute__((address_space(3))) void*)l, 16, 0, 0);
}

// asm ds_read: invisible to SIInsertWaitcnts' LDS-DMA alias drain (R7 win).
#define DSR(dst, preg, IMM) \
  asm volatile("ds_read_b128 %0, %1 offset:%c2" : "=&v"(dst) : "v"(preg), "n"(IMM))

#define SCHED0 __builtin_amdgcn_sched_barrier(0)
#define LGKM0 do { asm volatile("s_waitcnt lgkmcnt(0)"); SCHED0; } while (0)
#define LGKM2 do { asm volatile("s_waitcnt lgkmcnt(2)"); SCHED0; } while (0)
#define LGKM4 do { asm volatile("s_waitcnt lgkmcnt(4)"); SCHED0; } while (0)
#define LGKM6 do { asm volatile("s_waitcnt lgkmcnt(6)"); SCHED0; } while (0)
#define SBARR do { __builtin_amdgcn_s_barrier(); SCHED0; } while (0)
#define VMW4 do { asm volatile("s_waitcnt vmcnt(4)"); SCHED0; } while (0)
#define VMW0 do { asm volatile("s_waitcnt vmcnt(0)"); SCHED0; } while (0)

__global__ void k_init(unsigned* g_ord, unsigned* out_u) {
  int i = blockIdx.x * 256 + threadIdx.x;
  if (i < 64 * 512) { g_ord[i] = ORD_NEG_INF; out_u[i] = ORD_NEG_INF; }
}

__global__ void k_convX(const float* __restrict__ x, bf16* __restrict__ y, long n4) {
  long i = (long)blockIdx.x * 256 + threadIdx.x;
  long stride = (long)gridDim.x * 256;
  for (; i < n4; i += stride) {
    float4 v = ((const float4*)x)[i];
    bf16x4 o = {(bf16)v.x, (bf16)v.y, (bf16)v.z, (bf16)v.w};
    ((bf16x4*)y)[i] = o;
  }
}

// W [K][Nout] fp32 -> Wt [Nout][K] bf16
__global__ void k_convWt(const float* __restrict__ W, bf16* __restrict__ Wt, int K, int Nout) {
  int idx = blockIdx.x * 256 + threadIdx.x;
  if (idx < K * Nout) {
    int k = idx / Nout, c = idx - k * Nout;
    Wt[(size_t)c * K + k] = (bf16)W[idx];
  }
}

// sb[s][c] = b4[c] + sum_j g[s][j] * W4[128+j][c]
__global__ void k_segbias(const unsigned* __restrict__ g_ord, const float* __restrict__ W4,
                          const float* __restrict__ b4, float* __restrict__ sb) {
  const int s = blockIdx.x, c = threadIdx.x;
  __shared__ float gs[512];
  gs[c] = ord2f(g_ord[s * 512 + c]);
  __syncthreads();
  float acc = b4[c];
  for (int j = 0; j < 512; ++j) acc = fmaf(gs[j], W4[(size_t)(128 + j) * 512 + c], acc);
  sb[s * 512 + c] = acc;
}

__global__ void k_decode(unsigned* p, int n) {
  int i = blockIdx.x * 256 + threadIdx.x;
  if (i < n) { float f = ord2f(p[i]); ((float*)p)[i] = f; }
}

// 256x256 tile, 8 waves (wr 0..1 x wc 0..3), per-wave 128x64 output. BK=64.
// LDS layout: sMem[mat:2][half:2][dbuf:2][row:128][slot:8 x 16B] = 128 KiB.
//   stored slot = logical slot ^ bits  (both-sides; <=2-way on reads)
// 8 phases per iter (K-tiles 2t,2t+1). Phase: {k0 reads; k1 reads; 1 half
//   stage | lgkm(|k1|) | 8 MFMA k0 | lgkm0 | 8 MFMA k1 | barrier}.
// vmcnt(4) only at K-tile boundaries. Stage slots as R7/R13 (race-free).
template <int BIASMODE, bool RELU, int EPI, int K, int NOUT>
__launch_bounds__(512, 1)
__global__ void k_gemm(const bf16* __restrict__ A, const bf16* __restrict__ Bt,
                       const float* __restrict__ bias, const int* __restrict__ ids,
                       long row_off, bf16* __restrict__ out,
                       unsigned* __restrict__ outAtomic) {
  constexpr int NT = K / 64;    // 64-wide K-tiles
  constexpr int NIT = NT / 2;   // iterations, 2 K-tiles each
  constexpr int NBX = NOUT / 256;
  __shared__ __align__(16) char sMem[131072];
  __shared__ int sIds[256];
  const int tid = threadIdx.x;
  const int wid = tid >> 6, lane = tid & 63;
  const int wr = wid >> 2, wc = wid & 3;
  const int lr = lane & 15, lk = lane >> 4;

  // linear id (N fastest) -> bijective XCD swizzle (m204)
  const int nwg = NBX * (int)gridDim.y;
  const int orig = (int)blockIdx.y * NBX + (int)blockIdx.x;
  const int q = nwg >> 3, r = nwg & 7;
  const int xcd = orig & 7, lid = orig >> 3;
  const int wg = (xcd < r ? xcd * (q + 1) : r * (q + 1) + (xcd - r) * q) + lid;
  const int n0 = (wg % NBX) * 256;
  const int m0 = (wg / NBX) * 256;

  if constexpr (BIASMODE == 1 || EPI == 1) {
    if (tid < 256) {
      long gi = row_off + m0 + tid;
      if (gi > (long)N_PTS - 1) gi = (long)N_PTS - 1;
      sIds[tid] = ids[gi];
    }
  }
  SCHED0;

  // ---- staging geometry (verified R7/R13)
  const int row0 = (wid * 2) * 8 + (lane >> 3);
  const int row1 = row0 + 8;
  const int sc0 = ((lane & 7) ^ (lane >> 4)) * 8;
  const int sc1 = ((lane & 7) ^ (4 + (lane >> 4))) * 8;
  lds_char* lds3 = (lds_char*)sMem;

  auto stageH = [&](int tau, int mat, int h) {
    if (tau >= NT) return;
    const int db = tau & 1;
    const bf16* srcb = (mat == 0) ? A + (size_t)(m0 + h * 128) * K
                                  : Bt + (size_t)(n0 + h * 128) * K;
    lds_char* d0 = lds3 + mat * 65536 + h * 32768 + db * 16384 + (wid * 2) * 1024;
    gld16(srcb + (size_t)row0 * K + tau * 64 + sc0, d0);
    gld16(srcb + (size_t)row1 * K + tau * 64 + sc1, d0 + 1024);
  };

  // ---- fragment read bases (verified R7/R13)
  const unsigned s7 = (unsigned)(lr >> 1);
  const unsigned cks0 = (((unsigned)lk) ^ s7) * 16u;
  const unsigned cks1 = (((unsigned)lk + 4u) ^ s7) * 16u;
  lds_char* vA0 = lds3 + wr * 32768 + lr * 128 + cks0;
  lds_char* vA1 = lds3 + wr * 32768 + lr * 128 + cks1;
  lds_char* vB0 = lds3 + 65536 + (wc >> 1) * 32768 + (wc & 1) * 8192 + lr * 128 + cks0;
  lds_char* vB1 = lds3 + 65536 + (wc >> 1) * 32768 + (wc & 1) * 8192 + lr * 128 + cks1;

  bf16x8 aR[4][2], bR[4][2];
  f32x4 acc[8][4];
#pragma unroll
  for (int i = 0; i < 8; ++i)
#pragma unroll
    for (int j = 0; j < 4; ++j) acc[i][j] = {0.f, 0.f, 0.f, 0.f};

// k-split read issue: k0 set (vA0/vB0) then k1 set (vA1/vB1)
#define RD_A_K0(DB, IHI) do { \
  DSR(aR[0][0], vA0, (DB) + ((IHI) + 0) * 2048); DSR(aR[1][0], vA0, (DB) + ((IHI) + 1) * 2048); \
  DSR(aR[2][0], vA0, (DB) + ((IHI) + 2) * 2048); DSR(aR[3][0], vA0, (DB) + ((IHI) + 3) * 2048); \
} while (0)
#define RD_A_K1(DB, IHI) do { \
  DSR(aR[0][1], vA1, (DB) + ((IHI) + 0) * 2048); DSR(aR[1][1], vA1, (DB) + ((IHI) + 1) * 2048); \
  DSR(aR[2][1], vA1, (DB) + ((IHI) + 2) * 2048); DSR(aR[3][1], vA1, (DB) + ((IHI) + 3) * 2048); \
} while (0)
#define RD_B01_K0(DB) do { DSR(bR[0][0], vB0, (DB)); DSR(bR[1][0], vB0, (DB) + 2048); } while (0)
#define RD_B01_K1(DB) do { DSR(bR[0][1], vB1, (DB)); DSR(bR[1][1], vB1, (DB) + 2048); } while (0)
#define RD_B23_K0(DB) do { DSR(bR[2][0], vB0, (DB) + 4096); DSR(bR[3][0], vB0, (DB) + 6144); } while (0)
#define RD_B23_K1(DB) do { DSR(bR[2][1], vB1, (DB) + 4096); DSR(bR[3][1], vB1, (DB) + 6144); } while (0)
// 8 MFMAs of one k-slice; all hit distinct accumulators
#define MMK(II, JJ, KK) do { __builtin_amdgcn_s_setprio(1); \
  _Pragma("unroll") for (int i_ = 0; i_ < 4; ++i_) \
  _Pragma("unroll") for (int j_ = 0; j_ < 2; ++j_) \
    acc[(II) + i_][(JJ) + j_] = __builtin_amdgcn_mfma_f32_16x16x32_bf16(aR[i_][KK], bR[(JJ) + j_][KK], acc[(II) + i_][(JJ) + j_], 0, 0, 0); \
  __builtin_amdgcn_s_setprio(0); } while (0)

  // ---- prologue: stage tile0 fully + B halves of tile1 (deadline order)
  stageH(0, 1, 0); stageH(0, 1, 1); stageH(0, 0, 0); stageH(0, 0, 1);
  stageH(1, 1, 0); stageH(1, 1, 1);
  asm volatile("s_waitcnt vmcnt(4) lgkmcnt(0)");  // tile0 landed; sIds visible
  SCHED0;
  SBARR;

#pragma unroll 1
  for (int t = 0; t < NIT; ++t) {
    const int t2 = 2 * t;
    // p0 (tile 2t, dbuf0): 12 reads, k-split
    RD_A_K0(0, 0); RD_B01_K0(0);
    RD_A_K1(0, 0); RD_B01_K1(0);
    stageH(t2 + 1, 0, 0);
    LGKM6; MMK(0, 0, 0); LGKM0; MMK(0, 0, 1); SBARR;
    // p1: 4 reads
    RD_B23_K0(0); RD_B23_K1(0);
    stageH(t2 + 1, 0, 1);
    LGKM2; MMK(0, 2, 0); LGKM0; MMK(0, 2, 1); SBARR;
    // p2: 8 reads
    RD_A_K0(0, 4); RD_A_K1(0, 4);
    stageH(t2 + 2, 1, 0);
    LGKM4; MMK(4, 0, 0); LGKM0; MMK(4, 0, 1); SBARR;
    // p3: 0 reads
    stageH(t2 + 2, 1, 1);
    MMK(4, 2, 0); MMK(4, 2, 1);
    if (t < NIT - 1) VMW4; else VMW0;   // tile 2t+1 guaranteed after barrier
    SBARR;
    // p4 (tile 2t+1, dbuf1 = +16384): 12 reads
    RD_A_K0(16384, 0); RD_B01_K0(16384);
    RD_A_K1(16384, 0); RD_B01_K1(16384);
    stageH(t2 + 2, 0, 0);
    LGKM6; MMK(0, 0, 0); LGKM0; MMK(0, 0, 1); SBARR;
    // p5: 4 reads
    RD_B23_K0(16384); RD_B23_K1(16384);
    stageH(t2 + 2, 0, 1);
    LGKM2; MMK(0, 2, 0); LGKM0; MMK(0, 2, 1); SBARR;
    // p6: 8 reads
    RD_A_K0(16384, 4); RD_A_K1(16384, 4);
    stageH(t2 + 3, 1, 0);
    LGKM4; MMK(4, 0, 0); LGKM0; MMK(4, 0, 1); SBARR;
    // p7: 0 reads
    stageH(t2 + 3, 1, 1);
    MMK(4, 2, 0); MMK(4, 2, 1);
    if (t < NIT - 1) { VMW4; SBARR; }   // tile 2t+2 guaranteed for next p0
  }

  if constexpr (EPI == 0) {
#pragma unroll
    for (int j = 0; j < 4; ++j) {
      const int col = n0 + wc * 64 + j * 16 + lr;
      float bcol = (BIASMODE == 0) ? bias[col] : 0.f;
#pragma unroll
      for (int i = 0; i < 8; ++i) {
#pragma unroll
        for (int q2 = 0; q2 < 4; ++q2) {
          const int rl = wr * 128 + i * 16 + lk * 4 + q2;
          float v = acc[i][j][q2];
          if constexpr (BIASMODE == 0) v += bcol;
          else v += bias[(size_t)sIds[rl] * 512 + col];
          if constexpr (RELU) v = fmaxf(v, 0.f);
          out[(size_t)(m0 + rl) * NOUT + col] = (bf16)v;
        }
      }
    }
  } else {
    const int sLo = sIds[wr * 128], sHi = sIds[wr * 128 + 127];
#pragma unroll
    for (int j = 0; j < 4; ++j) {
      const int col = n0 + wc * 64 + j * 16 + lr;
      const float bcol = bias[col];
      for (int s = sLo; s <= sHi; ++s) {
        float m = -__builtin_inff();
#pragma unroll
        for (int i = 0; i < 8; ++i)
#pragma unroll
          for (int q2 = 0; q2 < 4; ++q2) {
            const int rl = wr * 128 + i * 16 + lk * 4 + q2;
            const bool rv = (row_off + m0 + rl) < (long)N_PTS;  // pad rows share clamped id
            float v = acc[i][j][q2] + bcol;
            m = (sIds[rl] == s && rv) ? fmaxf(m, v) : m;
          }
        m = fmaxf(m, __shfl_xor(m, 16));
        m = fmaxf(m, __shfl_xor(m, 32));
        if (lane < 16) atomicMax(&outAtomic[(size_t)s * 512 + col], f2ord(m));
      }
    }
  }
#undef RD_A_K0
#undef RD_A_K1
#undef RD_B01_K0
#undef RD_B01_K1
#undef RD_B23_K0
#undef RD_B23_K1
#undef MMK
}

static inline long lmin(long a, long b) { return a < b ? a : b; }

extern "C" void kernel_launch(void* const* d_in, const int* in_sizes, int n_in,
                              void* d_out, int out_size, void* d_ws, size_t ws_size,
                              hipStream_t stream) {
  const float* pos = (const float*)d_in[0];
  const int* ids = (const int*)d_in[1];
  const float* W1 = (const float*)d_in[2]; const float* b1 = (const float*)d_in[3];
  const float* W2 = (const float*)d_in[4]; const float* b2 = (const float*)d_in[5];
  const float* W3 = (const float*)d_in[6]; const float* b3 = (const float*)d_in[7];
  const float* W4 = (const float*)d_in[8]; const float* b4 = (const float*)d_in[9];
  const float* W5 = (const float*)d_in[10]; const float* b5 = (const float*)d_in[11];

  char* ws = (char*)d_ws;
  size_t off = 0;
  auto alloc = [&](size_t bytes) -> char* {
    off = (off + 255) & ~(size_t)255;
    char* p = ws + off; off += bytes; return p;
  };
  bf16* Wt1  = (bf16*)alloc(128 * 256 * 2);
  bf16* Wt2  = (bf16*)alloc(256 * 512 * 2);
  bf16* Wt3  = (bf16*)alloc(512 * 512 * 2);
  bf16* Wt4a = (bf16*)alloc(128 * 512 * 2);
  bf16* Wt5  = (bf16*)alloc(512 * 512 * 2);
  unsigned* g_ord = (unsigned*)alloc(64 * 512 * 4);
  float* sb = (float*)alloc(64 * 512 * 4);
  // persistent bf16 X (+384 pad rows for the last 256-tile)
  bf16* Xbf = (bf16*)alloc((size_t)(N_PTS + 384) * 128 * 2);

  const size_t per_row = (256 + 512) * 2;  // h1 + h2
  size_t fixed_end = (off + 255) & ~(size_t)255;
  long avail = (long)ws_size - (long)fixed_end - 8192;
  long maxrows = avail / (long)per_row;
  long chunk = (maxrows - 256) & ~255L;  // chunk multiple of 256; +256 pad rows
  if (chunk > N_PTS) chunk = N_PTS;
  if (chunk < 256) chunk = 256;
  long rows_alloc = chunk + 256;

  bf16* h1 = (bf16*)alloc((size_t)rows_alloc * 256 * 2);
  bf16* h2 = (bf16*)alloc((size_t)rows_alloc * 512 * 2);  // also z1 in phase 2

  k_init<<<dim3(128), dim3(256), 0, stream>>>(g_ord, (unsigned*)d_out);
  k_convWt<<<dim3((128 * 256 + 255) / 256), dim3(256), 0, stream>>>(W1, Wt1, 128, 256);
  k_convWt<<<dim3((256 * 512 + 255) / 256), dim3(256), 0, stream>>>(W2, Wt2, 256, 512);
  k_convWt<<<dim3((512 * 512 + 255) / 256), dim3(256), 0, stream>>>(W3, Wt3, 512, 512);
  k_convWt<<<dim3((128 * 512 + 255) / 256), dim3(256), 0, stream>>>(W4, Wt4a, 128, 512);
  k_convWt<<<dim3((512 * 512 + 255) / 256), dim3(256), 0, stream>>>(W5, Wt5, 512, 512);
  // one full-N conversion; pad rows stay 0xAA poison (finite bf16, masked later)
  k_convX<<<dim3(2048), dim3(256), 0, stream>>>(pos, Xbf, (long)N_PTS * 32);

  // phase 1: mlp1 + fused segmax -> g_ord
  for (long o = 0; o < N_PTS; o += chunk) {
    long rows = lmin(chunk, N_PTS - o);
    unsigned mb = (unsigned)((rows + 255) / 256);
    k_gemm<0, true, 0, 128, 256><<<dim3(1, mb), dim3(512), 0, stream>>>(Xbf + o * 128, Wt1, b1, ids, o, h1, nullptr);
    k_gemm<0, true, 0, 256, 512><<<dim3(2, mb), dim3(512), 0, stream>>>(h1, Wt2, b2, ids, o, h2, nullptr);
    k_gemm<0, false, 1, 512, 512><<<dim3(2, mb), dim3(512), 0, stream>>>(h2, Wt3, b3, ids, o, nullptr, g_ord);
  }
  k_segbias<<<dim3(64), dim3(512), 0, stream>>>(g_ord, W4, b4, sb);
  // phase 2: z1 = relu(X@W4a + sb[seg]); out = segmax(z1@W5 + b5)
  for (long o = 0; o < N_PTS; o += chunk) {
    long rows = lmin(chunk, N_PTS - o);
    unsigned mb = (unsigned)((rows + 255) / 256);
    k_gemm<1, true, 0, 128, 512><<<dim3(2, mb), dim3(512), 0, stream>>>(Xbf + o * 128, Wt4a, sb, ids, o, h2, nullptr);
    k_gemm<0, false, 1, 512, 512><<<dim3(2, mb), dim3(512), 0, stream>>>(h2, Wt5, b5, ids, o, nullptr, (unsigned*)d_out);
  }
  k_decode<<<dim3(128), dim3(256), 0, stream>>>((unsigned*)d_out, 64 * 512);
}

// Round 17
// 1090.645 us; speedup vs baseline: 1.1005x; 1.0026x over previous
//
#include <hip/hip_runtime.h>
#include <stdint.h>

// GlobalEmdModel: mlp1(128->256->512->512) -> segmax -> segbias trick ->
// mlp2(X@W4a + sb[seg] -> 512 -> segmax) ; bf16 MFMA GEMMs, fp32 epilogues.
// R17: R16 + K=128 fully-resident fast path (L1, L4a): whole K fits LDS ->
//      stage all 8 half-tiles, ONE barrier, then free-run reads+MFMA with
//      counted lgkm only (no in-loop barriers / vmcnt / stage interleave).
//      K>=256 path byte-identical to R16 (best measured: 263us, 34% MfmaUtil).

typedef __bf16 bf16;
typedef __bf16 bf16x4 __attribute__((ext_vector_type(4)));
typedef __bf16 bf16x8 __attribute__((ext_vector_type(8)));
typedef float f32x4 __attribute__((ext_vector_type(4)));
typedef __attribute__((address_space(3))) char lds_char;

#define N_PTS 400000
#define ORD_NEG_INF 0x007FFFFFu  // f2ord(-inf)

__device__ __forceinline__ unsigned f2ord(float f) {
  unsigned u = __float_as_uint(f);
  return (u & 0x80000000u) ? ~u : (u | 0x80000000u);
}
__device__ __forceinline__ float ord2f(unsigned o) {
  unsigned u = (o & 0x80000000u) ? (o ^ 0x80000000u) : ~o;
  return __uint_as_float(u);
}

__device__ __forceinline__ void gld16(const bf16* g, lds_char* l) {
  __builtin_amdgcn_global_load_lds((const __attribute__((address_space(1))) void*)g,
                                   (__attribute__((address_space(3))) void*)l, 16, 0, 0);
}

// asm ds_read: invisible to SIInsertWaitcnts' LDS-DMA alias drain (R7 win).
#define DSR(dst, preg, IMM) \
  asm volatile("ds_read_b128 %0, %1 offset:%c2" : "=&v"(dst) : "v"(preg), "n"(IMM))

#define SCHED0 __builtin_amdgcn_sched_barrier(0)
#define LGKM0 do { asm volatile("s_waitcnt lgkmcnt(0)"); SCHED0; } while (0)
#define LGKM2 do { asm volatile("s_waitcnt lgkmcnt(2)"); SCHED0; } while (0)
#define LGKM4 do { asm volatile("s_waitcnt lgkmcnt(4)"); SCHED0; } while (0)
#define LGKM6 do { asm volatile("s_waitcnt lgkmcnt(6)"); SCHED0; } while (0)
#define SBARR do { __builtin_amdgcn_s_barrier(); SCHED0; } while (0)
#define VMW4 do { asm volatile("s_waitcnt vmcnt(4)"); SCHED0; } while (0)
#define VMW0 do { asm volatile("s_waitcnt vmcnt(0)"); SCHED0; } while (0)

__global__ void k_init(unsigned* g_ord, unsigned* out_u) {
  int i = blockIdx.x * 256 + threadIdx.x;
  if (i < 64 * 512) { g_ord[i] = ORD_NEG_INF; out_u[i] = ORD_NEG_INF; }
}

__global__ void k_convX(const float* __restrict__ x, bf16* __restrict__ y, long n4) {
  long i = (long)blockIdx.x * 256 + threadIdx.x;
  long stride = (long)gridDim.x * 256;
  for (; i < n4; i += stride) {
    float4 v = ((const float4*)x)[i];
    bf16x4 o = {(bf16)v.x, (bf16)v.y, (bf16)v.z, (bf16)v.w};
    ((bf16x4*)y)[i] = o;
  }
}

// W [K][Nout] fp32 -> Wt [Nout][K] bf16
__global__ void k_convWt(const float* __restrict__ W, bf16* __restrict__ Wt, int K, int Nout) {
  int idx = blockIdx.x * 256 + threadIdx.x;
  if (idx < K * Nout) {
    int k = idx / Nout, c = idx - k * Nout;
    Wt[(size_t)c * K + k] = (bf16)W[idx];
  }
}

// sb[s][c] = b4[c] + sum_j g[s][j] * W4[128+j][c]
__global__ void k_segbias(const unsigned* __restrict__ g_ord, const float* __restrict__ W4,
                          const float* __restrict__ b4, float* __restrict__ sb) {
  const int s = blockIdx.x, c = threadIdx.x;
  __shared__ float gs[512];
  gs[c] = ord2f(g_ord[s * 512 + c]);
  __syncthreads();
  float acc = b4[c];
  for (int j = 0; j < 512; ++j) acc = fmaf(gs[j], W4[(size_t)(128 + j) * 512 + c], acc);
  sb[s * 512 + c] = acc;
}

__global__ void k_decode(unsigned* p, int n) {
  int i = blockIdx.x * 256 + threadIdx.x;
  if (i < n) { float f = ord2f(p[i]); ((float*)p)[i] = f; }
}

// 256x256 tile, 8 waves (wr 0..1 x wc 0..3), per-wave 128x64 output. BK=64.
// LDS layout: sMem[mat:2][half:2][dbuf:2][row:128][slot:8 x 16B] = 128 KiB.
//   stored slot = logical slot ^ bits  (both-sides; <=2-way on reads)
// K>=256: 8 phases per iter, {k0 reads; k1 reads; 1 half stage | lgkm(|k1|) |
//   8 MFMA k0 | lgkm0 | 8 MFMA k1 | barrier}; vmcnt(4) at K-tile boundaries.
// K==128: whole K resident (dbuf dim holds both K-tiles) -> stage all, one
//   barrier, free-run phases with counted lgkm only (no hazards exist).
template <int BIASMODE, bool RELU, int EPI, int K, int NOUT>
__launch_bounds__(512, 1)
__global__ void k_gemm(const bf16* __restrict__ A, const bf16* __restrict__ Bt,
                       const float* __restrict__ bias, const int* __restrict__ ids,
                       long row_off, bf16* __restrict__ out,
                       unsigned* __restrict__ outAtomic) {
  constexpr int NT = K / 64;    // 64-wide K-tiles
  constexpr int NIT = NT / 2;   // iterations, 2 K-tiles each
  constexpr int NBX = NOUT / 256;
  __shared__ __align__(16) char sMem[131072];
  __shared__ int sIds[256];
  const int tid = threadIdx.x;
  const int wid = tid >> 6, lane = tid & 63;
  const int wr = wid >> 2, wc = wid & 3;
  const int lr = lane & 15, lk = lane >> 4;

  // linear id (N fastest) -> bijective XCD swizzle (m204)
  const int nwg = NBX * (int)gridDim.y;
  const int orig = (int)blockIdx.y * NBX + (int)blockIdx.x;
  const int q = nwg >> 3, r = nwg & 7;
  const int xcd = orig & 7, lid = orig >> 3;
  const int wg = (xcd < r ? xcd * (q + 1) : r * (q + 1) + (xcd - r) * q) + lid;
  const int n0 = (wg % NBX) * 256;
  const int m0 = (wg / NBX) * 256;

  if constexpr (BIASMODE == 1 || EPI == 1) {
    if (tid < 256) {
      long gi = row_off + m0 + tid;
      if (gi > (long)N_PTS - 1) gi = (long)N_PTS - 1;
      sIds[tid] = ids[gi];
    }
  }
  SCHED0;

  // ---- staging geometry (verified R7/R13)
  const int row0 = (wid * 2) * 8 + (lane >> 3);
  const int row1 = row0 + 8;
  const int sc0 = ((lane & 7) ^ (lane >> 4)) * 8;
  const int sc1 = ((lane & 7) ^ (4 + (lane >> 4))) * 8;
  lds_char* lds3 = (lds_char*)sMem;

  auto stageH = [&](int tau, int mat, int h) {
    if (tau >= NT) return;
    const int db = tau & 1;
    const bf16* srcb = (mat == 0) ? A + (size_t)(m0 + h * 128) * K
                                  : Bt + (size_t)(n0 + h * 128) * K;
    lds_char* d0 = lds3 + mat * 65536 + h * 32768 + db * 16384 + (wid * 2) * 1024;
    gld16(srcb + (size_t)row0 * K + tau * 64 + sc0, d0);
    gld16(srcb + (size_t)row1 * K + tau * 64 + sc1, d0 + 1024);
  };

  // ---- fragment read bases (verified R7/R13)
  const unsigned s7 = (unsigned)(lr >> 1);
  const unsigned cks0 = (((unsigned)lk) ^ s7) * 16u;
  const unsigned cks1 = (((unsigned)lk + 4u) ^ s7) * 16u;
  lds_char* vA0 = lds3 + wr * 32768 + lr * 128 + cks0;
  lds_char* vA1 = lds3 + wr * 32768 + lr * 128 + cks1;
  lds_char* vB0 = lds3 + 65536 + (wc >> 1) * 32768 + (wc & 1) * 8192 + lr * 128 + cks0;
  lds_char* vB1 = lds3 + 65536 + (wc >> 1) * 32768 + (wc & 1) * 8192 + lr * 128 + cks1;

  bf16x8 aR[4][2], bR[4][2];
  f32x4 acc[8][4];
#pragma unroll
  for (int i = 0; i < 8; ++i)
#pragma unroll
    for (int j = 0; j < 4; ++j) acc[i][j] = {0.f, 0.f, 0.f, 0.f};

// k-split read issue: k0 set (vA0/vB0) then k1 set (vA1/vB1)
#define RD_A_K0(DB, IHI) do { \
  DSR(aR[0][0], vA0, (DB) + ((IHI) + 0) * 2048); DSR(aR[1][0], vA0, (DB) + ((IHI) + 1) * 2048); \
  DSR(aR[2][0], vA0, (DB) + ((IHI) + 2) * 2048); DSR(aR[3][0], vA0, (DB) + ((IHI) + 3) * 2048); \
} while (0)
#define RD_A_K1(DB, IHI) do { \
  DSR(aR[0][1], vA1, (DB) + ((IHI) + 0) * 2048); DSR(aR[1][1], vA1, (DB) + ((IHI) + 1) * 2048); \
  DSR(aR[2][1], vA1, (DB) + ((IHI) + 2) * 2048); DSR(aR[3][1], vA1, (DB) + ((IHI) + 3) * 2048); \
} while (0)
#define RD_B01_K0(DB) do { DSR(bR[0][0], vB0, (DB)); DSR(bR[1][0], vB0, (DB) + 2048); } while (0)
#define RD_B01_K1(DB) do { DSR(bR[0][1], vB1, (DB)); DSR(bR[1][1], vB1, (DB) + 2048); } while (0)
#define RD_B23_K0(DB) do { DSR(bR[2][0], vB0, (DB) + 4096); DSR(bR[3][0], vB0, (DB) + 6144); } while (0)
#define RD_B23_K1(DB) do { DSR(bR[2][1], vB1, (DB) + 4096); DSR(bR[3][1], vB1, (DB) + 6144); } while (0)
// 8 MFMAs of one k-slice; all hit distinct accumulators
#define MMK(II, JJ, KK) do { __builtin_amdgcn_s_setprio(1); \
  _Pragma("unroll") for (int i_ = 0; i_ < 4; ++i_) \
  _Pragma("unroll") for (int j_ = 0; j_ < 2; ++j_) \
    acc[(II) + i_][(JJ) + j_] = __builtin_amdgcn_mfma_f32_16x16x32_bf16(aR[i_][KK], bR[(JJ) + j_][KK], acc[(II) + i_][(JJ) + j_], 0, 0, 0); \
  __builtin_amdgcn_s_setprio(0); } while (0)

  if constexpr (NIT == 1) {
    // ---- K=128 fully-resident: stage both K-tiles (8 half-tiles), ONE
    // barrier, then free-run. No buffer is ever overwritten -> no hazards.
    stageH(0, 1, 0); stageH(0, 1, 1); stageH(0, 0, 0); stageH(0, 0, 1);
    stageH(1, 1, 0); stageH(1, 1, 1); stageH(1, 0, 0); stageH(1, 0, 1);
    asm volatile("s_waitcnt vmcnt(0) lgkmcnt(0)");
    SCHED0;
    SBARR;
    // tile 0 (DB=0)
    RD_A_K0(0, 0); RD_B01_K0(0); RD_A_K1(0, 0); RD_B01_K1(0);
    LGKM6; MMK(0, 0, 0); LGKM0; MMK(0, 0, 1);
    RD_B23_K0(0); RD_B23_K1(0);
    LGKM2; MMK(0, 2, 0); LGKM0; MMK(0, 2, 1);
    RD_A_K0(0, 4); RD_A_K1(0, 4);
    LGKM4; MMK(4, 0, 0); LGKM0; MMK(4, 0, 1);
    MMK(4, 2, 0); MMK(4, 2, 1);
    // tile 1 (DB=16384)
    RD_A_K0(16384, 0); RD_B01_K0(16384); RD_A_K1(16384, 0); RD_B01_K1(16384);
    LGKM6; MMK(0, 0, 0); LGKM0; MMK(0, 0, 1);
    RD_B23_K0(16384); RD_B23_K1(16384);
    LGKM2; MMK(0, 2, 0); LGKM0; MMK(0, 2, 1);
    RD_A_K0(16384, 4); RD_A_K1(16384, 4);
    LGKM4; MMK(4, 0, 0); LGKM0; MMK(4, 0, 1);
    MMK(4, 2, 0); MMK(4, 2, 1);
  } else {
    // ---- K>=256: R16 ring path (verified best)
    // prologue: stage tile0 fully + B halves of tile1 (deadline order)
    stageH(0, 1, 0); stageH(0, 1, 1); stageH(0, 0, 0); stageH(0, 0, 1);
    stageH(1, 1, 0); stageH(1, 1, 1);
    asm volatile("s_waitcnt vmcnt(4) lgkmcnt(0)");  // tile0 landed; sIds visible
    SCHED0;
    SBARR;

#pragma unroll 1
    for (int t = 0; t < NIT; ++t) {
      const int t2 = 2 * t;
      // p0 (tile 2t, dbuf0): 12 reads, k-split
      RD_A_K0(0, 0); RD_B01_K0(0);
      RD_A_K1(0, 0); RD_B01_K1(0);
      stageH(t2 + 1, 0, 0);
      LGKM6; MMK(0, 0, 0); LGKM0; MMK(0, 0, 1); SBARR;
      // p1: 4 reads
      RD_B23_K0(0); RD_B23_K1(0);
      stageH(t2 + 1, 0, 1);
      LGKM2; MMK(0, 2, 0); LGKM0; MMK(0, 2, 1); SBARR;
      // p2: 8 reads
      RD_A_K0(0, 4); RD_A_K1(0, 4);
      stageH(t2 + 2, 1, 0);
      LGKM4; MMK(4, 0, 0); LGKM0; MMK(4, 0, 1); SBARR;
      // p3: 0 reads
      stageH(t2 + 2, 1, 1);
      MMK(4, 2, 0); MMK(4, 2, 1);
      if (t < NIT - 1) VMW4; else VMW0;   // tile 2t+1 guaranteed after barrier
      SBARR;
      // p4 (tile 2t+1, dbuf1 = +16384): 12 reads
      RD_A_K0(16384, 0); RD_B01_K0(16384);
      RD_A_K1(16384, 0); RD_B01_K1(16384);
      stageH(t2 + 2, 0, 0);
      LGKM6; MMK(0, 0, 0); LGKM0; MMK(0, 0, 1); SBARR;
      // p5: 4 reads
      RD_B23_K0(16384); RD_B23_K1(16384);
      stageH(t2 + 2, 0, 1);
      LGKM2; MMK(0, 2, 0); LGKM0; MMK(0, 2, 1); SBARR;
      // p6: 8 reads
      RD_A_K0(16384, 4); RD_A_K1(16384, 4);
      stageH(t2 + 3, 1, 0);
      LGKM4; MMK(4, 0, 0); LGKM0; MMK(4, 0, 1); SBARR;
      // p7: 0 reads
      stageH(t2 + 3, 1, 1);
      MMK(4, 2, 0); MMK(4, 2, 1);
      if (t < NIT - 1) { VMW4; SBARR; }   // tile 2t+2 guaranteed for next p0
    }
  }

  if constexpr (EPI == 0) {
#pragma unroll
    for (int j = 0; j < 4; ++j) {
      const int col = n0 + wc * 64 + j * 16 + lr;
      float bcol = (BIASMODE == 0) ? bias[col] : 0.f;
#pragma unroll
      for (int i = 0; i < 8; ++i) {
#pragma unroll
        for (int q2 = 0; q2 < 4; ++q2) {
          const int rl = wr * 128 + i * 16 + lk * 4 + q2;
          float v = acc[i][j][q2];
          if constexpr (BIASMODE == 0) v += bcol;
          else v += bias[(size_t)sIds[rl] * 512 + col];
          if constexpr (RELU) v = fmaxf(v, 0.f);
          out[(size_t)(m0 + rl) * NOUT + col] = (bf16)v;
        }
      }
    }
  } else {
    const int sLo = sIds[wr * 128], sHi = sIds[wr * 128 + 127];
#pragma unroll
    for (int j = 0; j < 4; ++j) {
      const int col = n0 + wc * 64 + j * 16 + lr;
      const float bcol = bias[col];
      for (int s = sLo; s <= sHi; ++s) {
        float m = -__builtin_inff();
#pragma unroll
        for (int i = 0; i < 8; ++i)
#pragma unroll
          for (int q2 = 0; q2 < 4; ++q2) {
            const int rl = wr * 128 + i * 16 + lk * 4 + q2;
            const bool rv = (row_off + m0 + rl) < (long)N_PTS;  // pad rows share clamped id
            float v = acc[i][j][q2] + bcol;
            m = (sIds[rl] == s && rv) ? fmaxf(m, v) : m;
          }
        m = fmaxf(m, __shfl_xor(m, 16));
        m = fmaxf(m, __shfl_xor(m, 32));
        if (lane < 16) atomicMax(&outAtomic[(size_t)s * 512 + col], f2ord(m));
      }
    }
  }
#undef RD_A_K0
#undef RD_A_K1
#undef RD_B01_K0
#undef RD_B01_K1
#undef RD_B23_K0
#undef RD_B23_K1
#undef MMK
}

static inline long lmin(long a, long b) { return a < b ? a : b; }

extern "C" void kernel_launch(void* const* d_in, const int* in_sizes, int n_in,
                              void* d_out, int out_size, void* d_ws, size_t ws_size,
                              hipStream_t stream) {
  const float* pos = (const float*)d_in[0];
  const int* ids = (const int*)d_in[1];
  const float* W1 = (const float*)d_in[2]; const float* b1 = (const float*)d_in[3];
  const float* W2 = (const float*)d_in[4]; const float* b2 = (const float*)d_in[5];
  const float* W3 = (const float*)d_in[6]; const float* b3 = (const float*)d_in[7];
  const float* W4 = (const float*)d_in[8]; const float* b4 = (const float*)d_in[9];
  const float* W5 = (const float*)d_in[10]; const float* b5 = (const float*)d_in[11];

  char* ws = (char*)d_ws;
  size_t off = 0;
  auto alloc = [&](size_t bytes) -> char* {
    off = (off + 255) & ~(size_t)255;
    char* p = ws + off; off += bytes; return p;
  };
  bf16* Wt1  = (bf16*)alloc(128 * 256 * 2);
  bf16* Wt2  = (bf16*)alloc(256 * 512 * 2);
  bf16* Wt3  = (bf16*)alloc(512 * 512 * 2);
  bf16* Wt4a = (bf16*)alloc(128 * 512 * 2);
  bf16* Wt5  = (bf16*)alloc(512 * 512 * 2);
  unsigned* g_ord = (unsigned*)alloc(64 * 512 * 4);
  float* sb = (float*)alloc(64 * 512 * 4);
  // persistent bf16 X (+384 pad rows for the last 256-tile)
  bf16* Xbf = (bf16*)alloc((size_t)(N_PTS + 384) * 128 * 2);

  const size_t per_row = (256 + 512) * 2;  // h1 + h2
  size_t fixed_end = (off + 255) & ~(size_t)255;
  long avail = (long)ws_size - (long)fixed_end - 8192;
  long maxrows = avail / (long)per_row;
  long chunk = (maxrows - 256) & ~255L;  // chunk multiple of 256; +256 pad rows
  if (chunk > N_PTS) chunk = N_PTS;
  if (chunk < 256) chunk = 256;
  long rows_alloc = chunk + 256;

  bf16* h1 = (bf16*)alloc((size_t)rows_alloc * 256 * 2);
  bf16* h2 = (bf16*)alloc((size_t)rows_alloc * 512 * 2);  // also z1 in phase 2

  k_init<<<dim3(128), dim3(256), 0, stream>>>(g_ord, (unsigned*)d_out);
  k_convWt<<<dim3((128 * 256 + 255) / 256), dim3(256), 0, stream>>>(W1, Wt1, 128, 256);
  k_convWt<<<dim3((256 * 512 + 255) / 256), dim3(256), 0, stream>>>(W2, Wt2, 256, 512);
  k_convWt<<<dim3((512 * 512 + 255) / 256), dim3(256), 0, stream>>>(W3, Wt3, 512, 512);
  k_convWt<<<dim3((128 * 512 + 255) / 256), dim3(256), 0, stream>>>(W4, Wt4a, 128, 512);
  k_convWt<<<dim3((512 * 512 + 255) / 256), dim3(256), 0, stream>>>(W5, Wt5, 512, 512);
  // one full-N conversion; pad rows stay 0xAA poison (finite bf16, masked later)
  k_convX<<<dim3(2048), dim3(256), 0, stream>>>(pos, Xbf, (long)N_PTS * 32);

  // phase 1: mlp1 + fused segmax -> g_ord
  for (long o = 0; o < N_PTS; o += chunk) {
    long rows = lmin(chunk, N_PTS - o);
    unsigned mb = (unsigned)((rows + 255) / 256);
    k_gemm<0, true, 0, 128, 256><<<dim3(1, mb), dim3(512), 0, stream>>>(Xbf + o * 128, Wt1, b1, ids, o, h1, nullptr);
    k_gemm<0, true, 0, 256, 512><<<dim3(2, mb), dim3(512), 0, stream>>>(h1, Wt2, b2, ids, o, h2, nullptr);
    k_gemm<0, false, 1, 512, 512><<<dim3(2, mb), dim3(512), 0, stream>>>(h2, Wt3, b3, ids, o, nullptr, g_ord);
  }
  k_segbias<<<dim3(64), dim3(512), 0, stream>>>(g_ord, W4, b4, sb);
  // phase 2: z1 = relu(X@W4a + sb[seg]); out = segmax(z1@W5 + b5)
  for (long o = 0; o < N_PTS; o += chunk) {
    long rows = lmin(chunk, N_PTS - o);
    unsigned mb = (unsigned)((rows + 255) / 256);
    k_gemm<1, true, 0, 128, 512><<<dim3(2, mb), dim3(512), 0, stream>>>(Xbf + o * 128, Wt4a, sb, ids, o, h2, nullptr);
    k_gemm<0, false, 1, 512, 512><<<dim3(2, mb), dim3(512), 0, stream>>>(h2, Wt5, b5, ids, o, nullptr, (unsigned*)d_out);
  }
  k_decode<<<dim3(128), dim3(256), 0, stream>>>((unsigned*)d_out, 64 * 512);
}